// Round 5
// baseline (231.186 us; speedup 1.0000x reference)
//
#include <hip/hip_runtime.h>
#include <stdint.h>

#define NROWS 4096
#define DIM   128
#define KB    8
#define NS    7            // K-1 negatives per anchor
#define TCH   16           // candidate chunks (256 cands each) [fallback path]
#define NPAIR 2048
#define HALF_CNT 58720256u // (4096*7*4096)/2

typedef __bf16 v8bf __attribute__((ext_vector_type(8)));
typedef float  v4f  __attribute__((ext_vector_type(4)));

__device__ __forceinline__ uint32_t rotl32(uint32_t x, int r) {
    return (x << r) | (x >> (32 - r));
}

// JAX threefry2x32, key = [0, 42], 20 rounds. (c0,c1)=(L, L+HALF_CNT):
// o0 = bits for flat index L, o1 = bits for flat index L+HALF_CNT.
__device__ __forceinline__ void threefry2x32(uint32_t c0, uint32_t c1,
                                             uint32_t& o0, uint32_t& o1) {
    const uint32_t ks0 = 0u;
    const uint32_t ks1 = 42u;
    const uint32_t ks2 = 0x1BD11BDAu ^ ks0 ^ ks1;
    uint32_t x0 = c0 + ks0;
    uint32_t x1 = c1 + ks1;
#define TF_R(r) { x0 += x1; x1 = rotl32(x1, r); x1 ^= x0; }
    TF_R(13) TF_R(15) TF_R(26) TF_R(6)
    x0 += ks1; x1 += ks2 + 1u;
    TF_R(17) TF_R(29) TF_R(16) TF_R(24)
    x0 += ks2; x1 += ks0 + 2u;
    TF_R(13) TF_R(15) TF_R(26) TF_R(6)
    x0 += ks0; x1 += ks1 + 3u;
    TF_R(17) TF_R(29) TF_R(16) TF_R(24)
    x0 += ks1; x1 += ks2 + 4u;
    TF_R(13) TF_R(15) TF_R(26) TF_R(6)
    x0 += ks2; x1 += ks0 + 5u;
#undef TF_R
    o0 = x0; o1 = x1;
}

// gumbel = -ln(-ln(u)), u = f + tiny, via native v_log_f32 (log2)
__device__ __forceinline__ float gumbel_of(uint32_t b) {
    float f = __uint_as_float((b >> 9) | 0x3f800000u) - 1.0f;   // [0,1)
    float u = f + 1.17549435e-38f;
    float l1 = __log2f(u);                    // <= 0
    float inner = -0.69314718055994531f * l1; // -ln(u) >= 0
    float l2 = __log2f(inner);
    return -0.69314718055994531f * l2;
}

// ---------------- kernel 1: normalize -> bf16 hi/lo planes + sq -----------
__global__ void knorm(const float* __restrict__ x, __bf16* __restrict__ xh,
                      __bf16* __restrict__ xl, float* __restrict__ sqv) {
    const int i = blockIdx.x;
    const int t = threadIdx.x;  // 64 threads, 2 elems each
    float2 v = ((const float2*)(x + (size_t)i * DIM))[t];
    float s = v.x * v.x + v.y * v.y;
#pragma unroll
    for (int m = 32; m > 0; m >>= 1) s += __shfl_xor(s, m, 64);
    float norm = sqrtf(s) + 1e-5f;
    float ox = v.x / norm, oy = v.y / norm;
    __bf16 hx = (__bf16)ox, hy = (__bf16)oy;
    float lx = ox - (float)hx, ly = oy - (float)hy;
    union { __bf16 b[2]; uint32_t u; } ph, pl;
    ph.b[0] = hx; ph.b[1] = hy;
    pl.b[0] = (__bf16)lx; pl.b[1] = (__bf16)ly;
    ((uint32_t*)xh)[i * 64 + t] = ph.u;
    ((uint32_t*)xl)[i * 64 + t] = pl.u;
    float s2 = ox * ox + oy * oy;
#pragma unroll
    for (int m = 32; m > 0; m >>= 1) s2 += __shfl_xor(s2, m, 64);
    if (t == 0) sqv[i] = s2;
}

// ---------------- kernel 2a: MFMA dists -> compacted candidate lists ------
// Same MFMA structure as before, j-loop removed. Per (pair p, cand t) with
// p = anchors (p, p+2048): if either row includes t, append {t, lg0, lg1}
// to pair p's list (ballot-compacted, atomic per-pair counters).
__global__ __launch_bounds__(256, 2) void kdist(
        const __bf16* __restrict__ xh, const __bf16* __restrict__ xl,
        const float* __restrict__ sqv,
        int* __restrict__ cnt, unsigned short* __restrict__ t16,
        float2* __restrict__ lgp) {
    const int lane  = threadIdx.x & 63;
    const int chunk = (blockIdx.x << 2) + (threadIdx.x >> 6);   // 0..15
    const int grp   = blockIdx.y;   // 0..255
    const int rlo = lane & 15;
    const int khi = lane >> 4;

    const int afr = grp * 8 + (rlo >> 1) + ((rlo & 1) << 11);
    v8bf ah[4], al[4];
#pragma unroll
    for (int ks = 0; ks < 4; ++ks) {
        const size_t off = (size_t)afr * DIM + ks * 32 + khi * 8;
        ah[ks] = *(const v8bf*)(xh + off);
        al[ks] = *(const v8bf*)(xl + off);
    }

    const int base = grp * 8 + khi * 2;   // pairA = base, pairB = base+1
    float sqA[4];
    sqA[0] = sqv[base];
    sqA[1] = sqv[base + 2048];
    sqA[2] = sqv[base + 1];
    sqA[3] = sqv[base + 2049];

    const int tcol0 = chunk * 256 + rlo;

    v8bf bhn[4], bln[4];
    float sqn;
    {
        const size_t boff = (size_t)tcol0 * DIM + khi * 8;
#pragma unroll
        for (int ks = 0; ks < 4; ++ks) {
            bhn[ks] = *(const v8bf*)(xh + boff + ks * 32);
            bln[ks] = *(const v8bf*)(xl + boff + ks * 32);
        }
        sqn = sqv[tcol0];
    }

#pragma unroll 1
    for (int cg = 0; cg < 16; ++cg) {
        v8bf bhc[4], blc[4];
#pragma unroll
        for (int ks = 0; ks < 4; ++ks) { bhc[ks] = bhn[ks]; blc[ks] = bln[ks]; }
        const float sqB = sqn;
        const int tcol = tcol0 + cg * 16;

        if (cg < 15) {
            const size_t boff = (size_t)(tcol + 16) * DIM + khi * 8;
#pragma unroll
            for (int ks = 0; ks < 4; ++ks) {
                bhn[ks] = *(const v8bf*)(xh + boff + ks * 32);
                bln[ks] = *(const v8bf*)(xl + boff + ks * 32);
            }
            sqn = sqv[tcol + 16];
        }

        v4f acc1 = {0.f, 0.f, 0.f, 0.f};
        v4f acc2 = {0.f, 0.f, 0.f, 0.f};
        v4f acc3 = {0.f, 0.f, 0.f, 0.f};
#pragma unroll
        for (int ks = 0; ks < 4; ++ks) {
            acc1 = __builtin_amdgcn_mfma_f32_16x16x32_bf16(ah[ks], bhc[ks], acc1, 0, 0, 0);
            acc2 = __builtin_amdgcn_mfma_f32_16x16x32_bf16(ah[ks], blc[ks], acc2, 0, 0, 0);
            acc3 = __builtin_amdgcn_mfma_f32_16x16x32_bf16(al[ks], bhc[ks], acc3, 0, 0, 0);
        }

        const int tBlk = tcol >> 3;
        const bool bd0 = (tBlk != grp);
        const bool bd1 = (tBlk != grp + 256);

        float lg[4];
        bool  ic[4];
#pragma unroll
        for (int q = 0; q < 4; ++q) {
            float dot = acc1[q] + acc2[q] + acc3[q];
            float d2  = fmaf(-2.0f, dot, sqA[q] + sqB);
            float l1  = __log2f(d2);
            float t2  = fmaf(-0.25f, d2, 1.0f);
            float l2  = __log2f(t2);
            float lw  = fmaf(-43.66827237527655f, l1, -43.32169878499658f * l2);
            bool incl = (d2 < 1.96f) && ((q & 1) ? bd1 : bd0);
            ic[q] = incl;
            lg[q] = incl ? lw : -INFINITY;
        }

        // compact-append per pair (union over the pair's two rows)
        const bool uA = ic[0] | ic[1];
        const bool uB = ic[2] | ic[3];
        unsigned long long ballA = __ballot(uA);
        unsigned long long ballB = __ballot(uB);
        unsigned int subA = (unsigned int)((ballA >> (khi * 16)) & 0xFFFFull);
        unsigned int subB = (unsigned int)((ballB >> (khi * 16)) & 0xFFFFull);
        int oldA = 0, oldB = 0;
        if (rlo == 0) {
            oldA = atomicAdd(&cnt[base], __popc(subA));
            oldB = atomicAdd(&cnt[base + 1], __popc(subB));
        }
        oldA = __shfl(oldA, khi * 16, 64);
        oldB = __shfl(oldB, khi * 16, 64);
        const unsigned int below = (1u << rlo) - 1u;
        if (uA) {
            int slot = oldA + __popc(subA & below);
            t16[(size_t)base * 4096 + slot] = (unsigned short)tcol;
            lgp[(size_t)base * 4096 + slot] = make_float2(lg[0], lg[1]);
        }
        if (uB) {
            int slot = oldB + __popc(subB & below);
            t16[(size_t)(base + 1) * 4096 + slot] = (unsigned short)tcol;
            lgp[(size_t)(base + 1) * 4096 + slot] = make_float2(lg[2], lg[3]);
        }
    }
}

// ---------------- kernel 2b: gumbel argmax over compacted lists -----------
// One block (4 waves) per pair. Each thread streams entries; 7 independent
// threefry chains per entry (unrolled) keep the VALU issue-saturated.
// Tie-break is the total order (v greater) || (v equal && t smaller), so
// the result is independent of entry order (= jnp.argmax first-index).
__global__ __launch_bounds__(256, 2) void kgum(
        const int* __restrict__ cnt, const unsigned short* __restrict__ t16,
        const float2* __restrict__ lgp, int* __restrict__ nidx) {
    const int p    = blockIdx.x;
    const int tid  = threadIdx.x;
    const int lane = tid & 63;
    const int wid  = tid >> 6;
    const int n    = cnt[p];
    const size_t bp = (size_t)p * 4096;
    const uint32_t pb = ((uint32_t)p * 7u) << 12;

    float bv[2][NS];
    int   bt[2][NS];
#pragma unroll
    for (int r = 0; r < 2; ++r)
#pragma unroll
        for (int j = 0; j < NS; ++j) { bv[r][j] = -INFINITY; bt[r][j] = 0x7FFFFFFF; }

#pragma unroll 1
    for (int e = tid; e < n; e += 256) {
        const uint32_t t = t16[bp + e];
        const float2 lg = lgp[bp + e];
#pragma unroll
        for (int j = 0; j < NS; ++j) {
            uint32_t L = pb + ((uint32_t)j << 12) + t;
            uint32_t o0, o1;
            threefry2x32(L, L + HALF_CNT, o0, o1);
            float v0 = lg.x + gumbel_of(o0);
            float v1 = lg.y + gumbel_of(o1);
            if (v0 > bv[0][j] || (v0 == bv[0][j] && (int)t < bt[0][j])) { bv[0][j] = v0; bt[0][j] = (int)t; }
            if (v1 > bv[1][j] || (v1 == bv[1][j] && (int)t < bt[1][j])) { bv[1][j] = v1; bt[1][j] = (int)t; }
        }
    }

    __shared__ float sV[4][2][NS];
    __shared__ int   sT[4][2][NS];
#pragma unroll
    for (int r = 0; r < 2; ++r)
#pragma unroll
        for (int j = 0; j < NS; ++j) {
            float v = bv[r][j];
            int   t = bt[r][j];
#pragma unroll
            for (int m = 1; m < 64; m <<= 1) {
                float v2 = __shfl_xor(v, m, 64);
                int   t2 = __shfl_xor(t, m, 64);
                if (v2 > v || (v2 == v && t2 < t)) { v = v2; t = t2; }
            }
            if (lane == 0) { sV[wid][r][j] = v; sT[wid][r][j] = t; }
        }
    __syncthreads();
    if (tid < 2 * NS) {
        const int r = tid / NS, j = tid - r * NS;
        float v = sV[0][r][j];
        int   t = sT[0][r][j];
#pragma unroll
        for (int w = 1; w < 4; ++w) {
            float v2 = sV[w][r][j];
            int   t2 = sT[w][r][j];
            if (v2 > v || (v2 == v && t2 < t)) { v = v2; t = t2; }
        }
        const int row = p + r * 2048;
        nidx[row * NS + j] = (v == -INFINITY) ? -1 : t;
    }
}

// ---------------- fallback kernel (small ws): fused ksample ---------------
__global__ __launch_bounds__(256, 2) void ksample(
        const __bf16* __restrict__ xh, const __bf16* __restrict__ xl,
        const float* __restrict__ sqv,
        float* __restrict__ pV, int* __restrict__ pI) {
    const int lane  = threadIdx.x & 63;
    const int chunk = (blockIdx.x << 2) + (threadIdx.x >> 6);
    const int grp   = blockIdx.y;
    const int rlo = lane & 15;
    const int khi = lane >> 4;

    const int afr = grp * 8 + (rlo >> 1) + ((rlo & 1) << 11);
    v8bf ah[4], al[4];
#pragma unroll
    for (int ks = 0; ks < 4; ++ks) {
        const size_t off = (size_t)afr * DIM + ks * 32 + khi * 8;
        ah[ks] = *(const v8bf*)(xh + off);
        al[ks] = *(const v8bf*)(xl + off);
    }
    const int base = grp * 8 + khi * 2;
    float sqA[4];
    sqA[0] = sqv[base];
    sqA[1] = sqv[base + 2048];
    sqA[2] = sqv[base + 1];
    sqA[3] = sqv[base + 2049];
    const uint32_t P0 = (uint32_t)base;
    const uint32_t P1 = (uint32_t)(base + 1);

    float    bestV[4][NS];
    uint32_t bestP[4];
#pragma unroll
    for (int q = 0; q < 4; ++q) {
        bestP[q] = 0u;
#pragma unroll
        for (int j = 0; j < NS; ++j) bestV[q][j] = -INFINITY;
    }
    const int tcol0 = chunk * 256 + rlo;

    v8bf bhn[4], bln[4];
    float sqn;
    {
        const size_t boff = (size_t)tcol0 * DIM + khi * 8;
#pragma unroll
        for (int ks = 0; ks < 4; ++ks) {
            bhn[ks] = *(const v8bf*)(xh + boff + ks * 32);
            bln[ks] = *(const v8bf*)(xl + boff + ks * 32);
        }
        sqn = sqv[tcol0];
    }

#pragma unroll 1
    for (int cg = 0; cg < 16; ++cg) {
        v8bf bhc[4], blc[4];
#pragma unroll
        for (int ks = 0; ks < 4; ++ks) { bhc[ks] = bhn[ks]; blc[ks] = bln[ks]; }
        const float sqB = sqn;
        const int tcol = tcol0 + cg * 16;
        if (cg < 15) {
            const size_t boff = (size_t)(tcol + 16) * DIM + khi * 8;
#pragma unroll
            for (int ks = 0; ks < 4; ++ks) {
                bhn[ks] = *(const v8bf*)(xh + boff + ks * 32);
                bln[ks] = *(const v8bf*)(xl + boff + ks * 32);
            }
            sqn = sqv[tcol + 16];
        }
        v4f acc1 = {0.f, 0.f, 0.f, 0.f};
        v4f acc2 = {0.f, 0.f, 0.f, 0.f};
        v4f acc3 = {0.f, 0.f, 0.f, 0.f};
#pragma unroll
        for (int ks = 0; ks < 4; ++ks) {
            acc1 = __builtin_amdgcn_mfma_f32_16x16x32_bf16(ah[ks], bhc[ks], acc1, 0, 0, 0);
            acc2 = __builtin_amdgcn_mfma_f32_16x16x32_bf16(ah[ks], blc[ks], acc2, 0, 0, 0);
            acc3 = __builtin_amdgcn_mfma_f32_16x16x32_bf16(al[ks], bhc[ks], acc3, 0, 0, 0);
        }
        const int tBlk = tcol >> 3;
        const bool bd0 = (tBlk != grp);
        const bool bd1 = (tBlk != grp + 256);
        float lg[4];
#pragma unroll
        for (int q = 0; q < 4; ++q) {
            float dot = acc1[q] + acc2[q] + acc3[q];
            float d2  = fmaf(-2.0f, dot, sqA[q] + sqB);
            float l1  = __log2f(d2);
            float t2  = fmaf(-0.25f, d2, 1.0f);
            float l2  = __log2f(t2);
            float lw  = fmaf(-43.66827237527655f, l1, -43.32169878499658f * l2);
            bool incl = (d2 < 1.96f) && ((q & 1) ? bd1 : bd0);
            lg[q] = incl ? lw : -INFINITY;
        }
        const uint32_t tB = (uint32_t)tcol;
#pragma unroll
        for (int j = 0; j < NS; ++j) {
            uint32_t L0 = ((P0 * 7u + (uint32_t)j) << 12) + tB;
            uint32_t L1 = ((P1 * 7u + (uint32_t)j) << 12) + tB;
            uint32_t o0, o1, o2, o3;
            threefry2x32(L0, L0 + HALF_CNT, o0, o1);
            threefry2x32(L1, L1 + HALF_CNT, o2, o3);
            float vv[4];
            vv[0] = lg[0] + gumbel_of(o0);
            vv[1] = lg[1] + gumbel_of(o1);
            vv[2] = lg[2] + gumbel_of(o2);
            vv[3] = lg[3] + gumbel_of(o3);
            const uint32_t keep = ~(0xFu << (4 * j));
            const uint32_t put  = ((uint32_t)cg) << (4 * j);
#pragma unroll
            for (int q = 0; q < 4; ++q) {
                bool gt = vv[q] > bestV[q][j];
                uint32_t np = (bestP[q] & keep) | put;
                bestV[q][j] = gt ? vv[q] : bestV[q][j];
                bestP[q]    = gt ? np : bestP[q];
            }
        }
    }
#pragma unroll
    for (int q = 0; q < 4; ++q) {
        const int a = base + (q >> 1) + ((q & 1) << 11);
#pragma unroll
        for (int j = 0; j < NS; ++j) {
            float v = bestV[q][j];
            int idx = tcol0 + (int)((bestP[q] >> (4 * j)) & 0xFu) * 16;
#pragma unroll
            for (int m = 1; m < 16; m <<= 1) {
                float v2 = __shfl_xor(v, m, 16);
                int   i2 = __shfl_xor(idx, m, 16);
                if (v2 > v || (v2 == v && i2 < idx)) { v = v2; idx = i2; }
            }
            if (rlo == 0) {
                size_t s = ((size_t)a * NS + j) * TCH + chunk;
                pV[s] = v;
                pI[s] = idx;
            }
        }
    }
}

__global__ void kcombine(const float* __restrict__ pV, const int* __restrict__ pI,
                         int* __restrict__ nidx) {
    int s = blockIdx.x * 256 + threadIdx.x;
    if (s >= NROWS * NS) return;
    float bv = -INFINITY;
    int bi = 0x7FFFFFFF;
#pragma unroll
    for (int c = 0; c < TCH; ++c) {
        float v = pV[(size_t)s * TCH + c];
        int idx = pI[(size_t)s * TCH + c];
        if (v > bv || (v == bv && idx < bi)) { bv = v; bi = idx; }
    }
    nidx[s] = (bv == -INFINITY) ? -1 : bi;
}

// ---------------- kernel 4: uniform fallback for invalid rows -------------
__global__ void kfixup(int* __restrict__ nidx) {
    const int i = blockIdx.x;
    if (nidx[(size_t)i * NS] >= 0) return;   // normal case: immediate exit
    const int lane = threadIdx.x;            // 64
    for (int j = 0; j < NS; ++j) {
        float bv = -INFINITY;
        int bi = 0x7FFFFFFF;
        for (int t = lane; t < NROWS; t += 64) {
            uint32_t o0, o1;
            float g;
            if (i < 2048) {
                uint32_t L = (((uint32_t)(i * NS + j)) << 12) + (uint32_t)t;
                threefry2x32(L, L + HALF_CNT, o0, o1);
                g = gumbel_of(o0);
            } else {
                uint32_t L = (((uint32_t)((i - 2048) * NS + j)) << 12) + (uint32_t)t;
                threefry2x32(L, L + HALF_CNT, o0, o1);
                g = gumbel_of(o1);
            }
            if (g > bv) { bv = g; bi = t; }
        }
#pragma unroll
        for (int m = 1; m < 64; m <<= 1) {
            float v2 = __shfl_xor(bv, m, 64);
            int   i2 = __shfl_xor(bi, m, 64);
            if (v2 > bv || (v2 == bv && i2 < bi)) { bv = v2; bi = i2; }
        }
        if (lane == 0) nidx[i * NS + j] = bi;
    }
}

// ---------------- kernel 5: triplet losses --------------------------------
__global__ void kloss(const float* __restrict__ x, const int* __restrict__ nidx,
                      float* __restrict__ loss) {
    int s = blockIdx.x * 256 + threadIdx.x;
    if (s >= NROWS * NS) return;
    int i = s / NS, j = s - i * NS;
    int r = i & (KB - 1), blk = i >> 3;
    int po = (j < r) ? j : j + 1;
    int p = blk * KB + po;
    int n = nidx[s] & (NROWS - 1);      // defensive clamp (no-op when correct)
    const float4* A  = (const float4*)(x + (size_t)i * DIM);
    const float4* P  = (const float4*)(x + (size_t)p * DIM);
    const float4* Ng = (const float4*)(x + (size_t)n * DIM);
    float sap = 0.0f, san = 0.0f;
#pragma unroll 8
    for (int k = 0; k < DIM / 4; ++k) {
        float4 a = A[k], pv = P[k], nv = Ng[k];
        float d;
        d = a.x - pv.x + 1e-6f; sap += d * d;
        d = a.y - pv.y + 1e-6f; sap += d * d;
        d = a.z - pv.z + 1e-6f; sap += d * d;
        d = a.w - pv.w + 1e-6f; sap += d * d;
        d = a.x - nv.x + 1e-6f; san += d * d;
        d = a.y - nv.y + 1e-6f; san += d * d;
        d = a.z - nv.z + 1e-6f; san += d * d;
        d = a.w - nv.w + 1e-6f; san += d * d;
    }
    loss[s] = fmaxf(sqrtf(sap) - sqrtf(san) + 1.0f, 0.0f);
}

// ---------------- kernel 6: mean ------------------------------------------
__global__ void kreduce(const float* __restrict__ loss, float* __restrict__ out) {
    __shared__ float part[4];
    const int tid = threadIdx.x;
    float sum = 0.0f;
    for (int s = tid; s < NROWS * NS; s += 256) sum += loss[s];
#pragma unroll
    for (int m = 32; m > 0; m >>= 1) sum += __shfl_xor(sum, m, 64);
    if ((tid & 63) == 0) part[tid >> 6] = sum;
    __syncthreads();
    if (tid == 0) out[0] = (part[0] + part[1] + part[2] + part[3]) / 28672.0f;
}

extern "C" void kernel_launch(void* const* d_in, const int* in_sizes, int n_in,
                              void* d_out, int out_size, void* d_ws, size_t ws_size,
                              hipStream_t stream) {
    const float* x = (const float*)d_in[0];
    float* out = (float*)d_out;

    uint8_t* w = (uint8_t*)d_ws;
    size_t off = 0;
    auto take = [&](size_t bytes) {
        void* p = w + off;
        off = (off + bytes + 255) & ~(size_t)255;
        return p;
    };
    __bf16* xh   = (__bf16*)take((size_t)NROWS * DIM * 2);
    __bf16* xl   = (__bf16*)take((size_t)NROWS * DIM * 2);
    float*  sqv  = (float*)take((size_t)NROWS * 4);
    int*    nidx = (int*)take((size_t)NROWS * NS * 4);
    float*  loss = (float*)take((size_t)NROWS * NS * 4);
    int*    cnt  = (int*)take((size_t)NPAIR * 4);
    const size_t prefix = off;
    // big path: compacted lists
    const size_t t16_b = (size_t)NPAIR * 4096 * 2;
    const size_t lgp_b = (size_t)NPAIR * 4096 * 8;
    const size_t NEED_BIG = prefix + ((t16_b + 255) & ~(size_t)255) + lgp_b;

    knorm<<<NROWS, 64, 0, stream>>>(x, xh, xl, sqv);

    if (ws_size >= NEED_BIG) {
        unsigned short* t16 = (unsigned short*)take(t16_b);
        float2*         lgp = (float2*)take(lgp_b);
        hipMemsetAsync(cnt, 0, NPAIR * sizeof(int), stream);
        kdist<<<dim3(TCH / 4, 256), 256, 0, stream>>>(xh, xl, sqv, cnt, t16, lgp);
        kgum<<<NPAIR, 256, 0, stream>>>(cnt, t16, lgp, nidx);
    } else {
        float* pV = (float*)take((size_t)NROWS * NS * TCH * 4);
        int*   pI = (int*)take((size_t)NROWS * NS * TCH * 4);
        ksample<<<dim3(TCH / 4, 256), 256, 0, stream>>>(xh, xl, sqv, pV, pI);
        kcombine<<<(NROWS * NS + 255) / 256, 256, 0, stream>>>(pV, pI, nidx);
    }

    kfixup<<<NROWS, 64, 0, stream>>>(nidx);
    kloss<<<(NROWS * NS + 255) / 256, 256, 0, stream>>>(x, nidx, loss);
    kreduce<<<1, 256, 0, stream>>>(loss, out);
}